// Round 10
// baseline (132.314 us; speedup 1.0000x reference)
//
#include <hip/hip_runtime.h>
#include <hip/hip_bf16.h>
#include <math.h>

#define BATCH_N 8192
#define K_DIM   2048
#define CLS     1000

typedef __attribute__((ext_vector_type(8))) short short8;
typedef __attribute__((ext_vector_type(8))) unsigned short ushort8;
typedef __attribute__((ext_vector_type(4))) float floatx4;

static __device__ __forceinline__ float softplus_fast(float z) {
    return fmaxf(z, 0.f) + __logf(1.f + __expf(-fabsf(z)));
}

static __device__ __forceinline__ void gld_lds16(const void* g, void* l) {
    __builtin_amdgcn_global_load_lds(
        (const __attribute__((address_space(1))) void*)g,
        (__attribute__((address_space(3))) void*)l, 16, 0, 0);
}

static __device__ __forceinline__ ushort f2bfr(float f) {
    return __hip_bfloat16_raw(__float2bfloat16(f)).x;
}

#define BARX  __builtin_amdgcn_s_barrier()
#define LGKM0 asm volatile("s_waitcnt lgkmcnt(0)" ::: "memory")
#define VMW(n) asm volatile("s_waitcnt vmcnt(" #n ")" ::: "memory")
#define SB0   __builtin_amdgcn_sched_barrier(0)
#define PRIO1 __builtin_amdgcn_s_setprio(1)
#define PRIO0 __builtin_amdgcn_s_setprio(0)

constexpr int NT = K_DIM / 32;   // 64 K-tiles

// ---- W -> bf16 "LDS image": img[bx][t][q] = exact 16KB chunk sequence the
// GEMM's B slot wants (pre-swizzled, zero-padded rows >= 1000). 4MB per GEMM.
// chunk q: p=q>>3, c8l=(q&7)^(p&7), r=2p+(c8l>>2), k=(c8l&3)*8 + t*32.
__global__ __launch_bounds__(256)
void make_wimg(const float* __restrict__ wx, const float* __restrict__ wy,
               ushort* __restrict__ imgx, ushort* __restrict__ imgy)
{
    const float* src = blockIdx.z ? wy : wx;
    ushort* dst      = blockIdx.z ? imgy : imgx;
    int c = blockIdx.x * 256 + threadIdx.x;       // 0..262143
    int q  = c & 1023;
    int t  = (c >> 10) & 63;
    int bx = c >> 16;
    int p = q >> 3, c8 = q & 7, c8l = c8 ^ (p & 7);
    int r = 2 * p + (c8l >> 2);
    int k = (c8l & 3) * 8 + t * 32;
    int row = bx * 256 + r;
    ushort8 v = (ushort8)0;
    if (row < CLS) {
        float4 a = *(const float4*)(src + (size_t)row * K_DIM + k);
        float4 b = *(const float4*)(src + (size_t)row * K_DIM + k + 4);
#pragma unroll
        for (int j = 0; j < 4; ++j) {
            v[j]     = f2bfr(((const float*)&a)[j]);
            v[j + 4] = f2bfr(((const float*)&b)[j]);
        }
    }
    *(ushort8*)(dst + (size_t)c * 8) = v;
}

// ---- 256x256 GEMM: A = fused fp32->bf16 reg-cvt (round-7 proven), B = DMA
// gld_lds from the pre-swizzled W image (no regs/cvt/ds_write for B).
// 8 waves (2 wr x 4 wc), per-wave 128x64 out, BK=32, 2-slot dbuf, 1 bar/tile.
// vmcnt ledger (in-order retirement): B(t+1) issued FIRST after the barrier
// (SB0 pins), A(t+2) reg-loads issued last => vmcnt(8) at the closing barrier
// drains exactly B(t+1); compiler's own vmcnt(2) at CVTW drains A(t+1).
__global__ __launch_bounds__(512, 2)
void gemm_fused2(const float* __restrict__ Xa, const float* __restrict__ Xb,
                 const ushort* __restrict__ imgx, const ushort* __restrict__ imgy,
                 const float* __restrict__ biasa, const float* __restrict__ biasb,
                 float* __restrict__ outa, float* __restrict__ outb)
{
    // bijective XCD swizzle over the 256-block grid (256 % 8 == 0)
    int flat = blockIdx.x + 4 * (blockIdx.y + 32 * blockIdx.z);
    int sw   = (flat & 7) * 32 + (flat >> 3);
    const int bx = sw & 3, by = (sw >> 2) & 31, bz = sw >> 7;

    const float* A     = bz ? Xb : Xa;      // [8192][2048] fp32
    const ushort* Wimg = bz ? imgy : imgx;  // [4][64][1024*8] bf16 image
    const float* bias  = bz ? biasb : biasa;
    float* out         = bz ? outb : outa;

    __shared__ ushort As[2][256 * 32];      // 16 KiB per slot
    __shared__ ushort Bs[2][256 * 32];

    const int tid  = threadIdx.x;
    const int lane = tid & 63;
    const int wid  = tid >> 6;              // 8 waves: wr in {0,1}, wc in {0..3}
    const int wr = wid >> 2, wc = wid & 3;
    const int fr = lane & 15, fg = lane >> 4;
    const int brow = by * 256;
    const int bcol = bx * 256;

    // A staging map: 1024 chunks, 2 per thread (swizzled source, linear dest)
    size_t a_g[2];
    int    l_of[2];
#pragma unroll
    for (int i = 0; i < 2; ++i) {
        int q = tid + i * 512;
        int p = q >> 3, c8 = q & 7, c8l = c8 ^ (p & 7);
        int r = 2 * p + (c8l >> 2);
        a_g[i] = (size_t)(brow + r) * K_DIM + (c8l & 3) * 8;
        l_of[i] = q * 8;                    // ushorts
    }
    const ushort* wbase = Wimg + (size_t)bx * 64 * 1024 * 8;

    // fragment-read offsets (verified layout)
    int afoff[8], bfoff[4];
#pragma unroll
    for (int m = 0; m < 8; ++m) {
        int row = wr * 128 + m * 16 + fr;
        int p = row >> 1;
        int c = (((row & 1) << 2) | fg) ^ (p & 7);
        afoff[m] = (p * 8 + c) * 8;
    }
#pragma unroll
    for (int n = 0; n < 4; ++n) {
        int row = wc * 64 + n * 16 + fr;
        int p = row >> 1;
        int c = (((row & 1) << 2) | fg) ^ (p & 7);
        bfoff[n] = (p * 8 + c) * 8;
    }

    floatx4 acc[8][4];
#pragma unroll
    for (int m = 0; m < 8; ++m)
#pragma unroll
        for (int n = 0; n < 4; ++n)
            acc[m][n] = (floatx4){0.f, 0.f, 0.f, 0.f};

    float4 ga[2][2];                        // staged A fp32 (tile in flight)

#define LOADT(t_) {                                                           \
    const size_t kb_ = (size_t)(t_) * 32;                                     \
    ga[0][0] = *(const float4*)(A + a_g[0] + kb_);                            \
    ga[0][1] = *(const float4*)(A + a_g[0] + kb_ + 4);                        \
    ga[1][0] = *(const float4*)(A + a_g[1] + kb_);                            \
    ga[1][1] = *(const float4*)(A + a_g[1] + kb_ + 4);                        \
}

#define CVTW(sl_) {                                                           \
    _Pragma("unroll")                                                         \
    for (int i = 0; i < 2; ++i) {                                             \
        ushort8 ta;                                                           \
        _Pragma("unroll")                                                     \
        for (int j = 0; j < 4; ++j) {                                         \
            ta[j]     = f2bfr(((const float*)&ga[i][0])[j]);                  \
            ta[j + 4] = f2bfr(((const float*)&ga[i][1])[j]);                  \
        }                                                                     \
        *(ushort8*)&As[sl_][l_of[i]] = ta;                                    \
    }                                                                         \
}

#define STAGE_B(t_) {                                                         \
    const ushort* s_ = wbase + (size_t)(t_) * 1024 * 8;                       \
    gld_lds16(s_ + (size_t)tid * 8,         &Bs[(t_) & 1][tid * 8]);          \
    gld_lds16(s_ + (size_t)(tid + 512) * 8, &Bs[(t_) & 1][(tid + 512) * 8]); \
}

    // prologue: B(0) DMA; A(0) load+cvt+write (compiler's wait drains B0 too);
    // A(1) loads in flight.
    STAGE_B(0)
    LOADT(0)
    CVTW(0)
    LOADT(1)
    VMW(8);                                 // no-op unless B0 still pending
    LGKM0; BARX; SB0;

#pragma unroll 1
    for (int t = 0; t < NT; ++t) {
        if (t + 1 < NT) STAGE_B(t + 1)      // issued FIRST: oldest VMEM ops
        SB0;                                // pin issue order (A loads below)

        const ushort* asl = &As[t & 1][0];
        const ushort* bsl = &Bs[t & 1][0];
        short8 af[8], bf[4];
#pragma unroll
        for (int m = 0; m < 8; ++m) af[m] = *(const short8*)(asl + afoff[m]);
#pragma unroll
        for (int n = 0; n < 4; ++n) bf[n] = *(const short8*)(bsl + bfoff[n]);

        PRIO1;
#pragma unroll
        for (int m = 0; m < 8; ++m)
#pragma unroll
            for (int n = 0; n < 4; ++n)
                acc[m][n] = __builtin_amdgcn_mfma_f32_16x16x32_bf16(
                    af[m], bf[n], acc[m][n], 0, 0, 0);
        PRIO0;

        if (t + 1 < NT) CVTW((t + 1) & 1)   // consumes A loads of tile t+1
        if (t + 2 < NT) LOADT(t + 2)        // issue early; newest VMEM ops
        SB0;
        if (t + 1 < NT) {
            if (t + 2 < NT) { VMW(8); }     // drains exactly B(t+1)
            else           { VMW(0); }      // tail: no A loads outstanding
            LGKM0; BARX; SB0;
        }
    }

    // epilogue: alpha = softplus(z + bias) + 1, predicated on col < 1000
#pragma unroll
    for (int n = 0; n < 4; ++n) {
        int col = bcol + wc * 64 + n * 16 + fr;
        if (col >= CLS) continue;
        float bv = bias[col];
#pragma unroll
        for (int m = 0; m < 8; ++m) {
#pragma unroll
            for (int j = 0; j < 4; ++j) {
                int row = brow + wr * 128 + m * 16 + fg * 4 + j;
                float z = acc[m][n][j] + bv;
                out[(size_t)row * CLS + col] = softplus_fast(z) + 1.f;
            }
        }
    }
}

// ---- fallback (no workspace): round-7 kernel verbatim ----
__global__ __launch_bounds__(512, 2)
void gemm_fused(const float* __restrict__ Xa, const float* __restrict__ Xb,
                const float* __restrict__ Wa, const float* __restrict__ Wb,
                const float* __restrict__ biasa, const float* __restrict__ biasb,
                float* __restrict__ outa, float* __restrict__ outb)
{
    int flat = blockIdx.x + 4 * (blockIdx.y + 32 * blockIdx.z);
    int sw   = (flat & 7) * 32 + (flat >> 3);
    const int bx = sw & 3, by = (sw >> 2) & 31, bz = sw >> 7;

    const float* A    = bz ? Xb : Xa;
    const float* B    = bz ? Wb : Wa;
    const float* bias = bz ? biasb : biasa;
    float* out        = bz ? outb : outa;

    __shared__ ushort As[2][256 * 32];
    __shared__ ushort Bs[2][256 * 32];

    const int tid  = threadIdx.x;
    const int lane = tid & 63;
    const int wid  = tid >> 6;
    const int wr = wid >> 2, wc = wid & 3;
    const int fr = lane & 15, fg = lane >> 4;
    const int brow = by * 256;
    const int bcol = bx * 256;

    size_t a_g[2], b_g[2];
    int    l_of[2];
#pragma unroll
    for (int i = 0; i < 2; ++i) {
        int q = tid + i * 512;
        int p = q >> 3, c8 = q & 7, c8l = c8 ^ (p & 7);
        int r = 2 * p + (c8l >> 2);
        int k = (c8l & 3) * 8;
        a_g[i] = (size_t)(brow + r) * K_DIM + k;
        int wrow = bcol + r; if (wrow >= CLS) wrow = CLS - 1;
        b_g[i] = (size_t)wrow * K_DIM + k;
        l_of[i] = q * 8;
    }

    int afoff[8], bfoff[4];
#pragma unroll
    for (int m = 0; m < 8; ++m) {
        int row = wr * 128 + m * 16 + fr;
        int p = row >> 1;
        int c = (((row & 1) << 2) | fg) ^ (p & 7);
        afoff[m] = (p * 8 + c) * 8;
    }
#pragma unroll
    for (int n = 0; n < 4; ++n) {
        int row = wc * 64 + n * 16 + fr;
        int p = row >> 1;
        int c = (((row & 1) << 2) | fg) ^ (p & 7);
        bfoff[n] = (p * 8 + c) * 8;
    }

    floatx4 acc[8][4];
#pragma unroll
    for (int m = 0; m < 8; ++m)
#pragma unroll
        for (int n = 0; n < 4; ++n)
            acc[m][n] = (floatx4){0.f, 0.f, 0.f, 0.f};

    float4 ga[2][2], gb[2][2];

#define FLOADT(t_) {                                                          \
    const size_t kb_ = (size_t)(t_) * 32;                                     \
    ga[0][0] = *(const float4*)(A + a_g[0] + kb_);                            \
    ga[0][1] = *(const float4*)(A + a_g[0] + kb_ + 4);                        \
    ga[1][0] = *(const float4*)(A + a_g[1] + kb_);                            \
    ga[1][1] = *(const float4*)(A + a_g[1] + kb_ + 4);                        \
    gb[0][0] = *(const float4*)(B + b_g[0] + kb_);                            \
    gb[0][1] = *(const float4*)(B + b_g[0] + kb_ + 4);                        \
    gb[1][0] = *(const float4*)(B + b_g[1] + kb_);                            \
    gb[1][1] = *(const float4*)(B + b_g[1] + kb_ + 4);                        \
}
#define FCVTW(sl_) {                                                          \
    _Pragma("unroll")                                                         \
    for (int i = 0; i < 2; ++i) {                                             \
        ushort8 ta, tb;                                                       \
        _Pragma("unroll")                                                     \
        for (int j = 0; j < 4; ++j) {                                         \
            ta[j]     = f2bfr(((const float*)&ga[i][0])[j]);                  \
            ta[j + 4] = f2bfr(((const float*)&ga[i][1])[j]);                  \
            tb[j]     = f2bfr(((const float*)&gb[i][0])[j]);                  \
            tb[j + 4] = f2bfr(((const float*)&gb[i][1])[j]);                  \
        }                                                                     \
        *(ushort8*)&As[sl_][l_of[i]] = ta;                                    \
        *(ushort8*)&Bs[sl_][l_of[i]] = tb;                                    \
    }                                                                         \
}

    FLOADT(0)
    FCVTW(0)
    FLOADT(1)
    SB0; LGKM0; BARX; SB0;

#pragma unroll 1
    for (int t = 0; t < NT; ++t) {
        const ushort* asl = &As[t & 1][0];
        const ushort* bsl = &Bs[t & 1][0];
        short8 af[8], bf[4];
#pragma unroll
        for (int m = 0; m < 8; ++m) af[m] = *(const short8*)(asl + afoff[m]);
#pragma unroll
        for (int n = 0; n < 4; ++n) bf[n] = *(const short8*)(bsl + bfoff[n]);

        PRIO1;
#pragma unroll
        for (int m = 0; m < 8; ++m)
#pragma unroll
            for (int n = 0; n < 4; ++n)
                acc[m][n] = __builtin_amdgcn_mfma_f32_16x16x32_bf16(
                    af[m], bf[n], acc[m][n], 0, 0, 0);
        PRIO0;

        if (t + 1 < NT) FCVTW((t + 1) & 1)
        if (t + 2 < NT) FLOADT(t + 2)
        SB0; LGKM0; BARX; SB0;
    }

#pragma unroll
    for (int n = 0; n < 4; ++n) {
        int col = bcol + wc * 64 + n * 16 + fr;
        if (col >= CLS) continue;
        float bv = bias[col];
#pragma unroll
        for (int m = 0; m < 8; ++m) {
#pragma unroll
            for (int j = 0; j < 4; ++j) {
                int row = brow + wr * 128 + m * 16 + fg * 4 + j;
                float z = acc[m][n][j] + bv;
                out[(size_t)row * CLS + col] = softplus_fast(z) + 1.f;
            }
        }
    }
}

// ---------------- DS combine: one wave per row, shuffle-xor reduce ----------

__global__ __launch_bounds__(256)
void ds_combine(const float* __restrict__ AX, const float* __restrict__ AY,
                float* __restrict__ out)
{
    const int row = blockIdx.x * 4 + (threadIdx.x >> 6);
    const int l = threadIdx.x & 63;
    const float* ax = AX + (size_t)row * CLS;
    const float* ay = AY + (size_t)row * CLS;

    float4 vx[4], vy[4];
    float sx = 0.f, sy = 0.f, sp = 0.f;
#pragma unroll
    for (int c = 0; c < 4; ++c) {
        int idx = l + c * 64;
        if (idx < CLS / 4) {
            vx[c] = *(const float4*)(ax + idx * 4);
            vy[c] = *(const float4*)(ay + idx * 4);
            const float* px = (const float*)&vx[c];
            const float* py = (const float*)&vy[c];
#pragma unroll
            for (int j = 0; j < 4; ++j) {
                sx += px[j]; sy += py[j];
                sp += (px[j] - 1.f) * (py[j] - 1.f);
            }
        }
    }
#pragma unroll
    for (int off = 1; off < 64; off <<= 1) {
        sx += __shfl_xor(sx, off);
        sy += __shfl_xor(sy, off);
        sp += __shfl_xor(sp, off);
    }
    const float S1 = sx, S2 = sy, P = sp;
    const float i1 = 1.f / S1, i2 = 1.f / S2;
    const float u1 = (float)CLS * i1, u2 = (float)CLS * i2;
    const float sb1 = (S1 - (float)CLS) * i1;
    const float sb2 = (S2 - (float)CLS) * i2;
    const float conf = sb1 * sb2 - P * i1 * i2;
    const float denom = 1.f - conf;
    const float idenom = 1.f / denom;
    const float Sa = (float)CLS * denom / (u1 * u2);

#pragma unroll
    for (int c = 0; c < 4; ++c) {
        int idx = l + c * 64;
        if (idx < CLS / 4) {
            float4 vo;
            const float* px = (const float*)&vx[c];
            const float* py = (const float*)&vy[c];
            float* po = (float*)&vo;
#pragma unroll
            for (int j = 0; j < 4; ++j) {
                float b1 = (px[j] - 1.f) * i1;
                float b2 = (py[j] - 1.f) * i2;
                float ba = (b1 * b2 + b1 * u2 + b2 * u1) * idenom;
                po[j] = ba * Sa + 1.f;
            }
            *(float4*)(out + (size_t)row * CLS + idx * 4) = vo;
        }
    }
}

extern "C" void kernel_launch(void* const* d_in, const int* in_sizes, int n_in,
                              void* d_out, int out_size, void* d_ws, size_t ws_size,
                              hipStream_t stream) {
    const float* x  = (const float*)d_in[0];
    const float* y  = (const float*)d_in[1];
    const float* Wx = (const float*)d_in[2];
    const float* bx = (const float*)d_in[3];
    const float* Wy = (const float*)d_in[4];
    const float* by = (const float*)d_in[5];
    float* out = (float*)d_out;
    float* ax = out + (size_t)BATCH_N * CLS;
    float* ay = ax  + (size_t)BATCH_N * CLS;

    const size_t IMG = (size_t)4 * 64 * 1024 * 8;         // ushorts per GEMM
    const size_t need = 2 * IMG * sizeof(ushort);         // 8.4 MB

    if (ws_size >= need) {
        ushort* imgx = (ushort*)d_ws;
        ushort* imgy = imgx + IMG;
        make_wimg<<<dim3(1024, 1, 2), 256, 0, stream>>>(Wx, Wy, imgx, imgy);
        gemm_fused2<<<dim3(4, 32, 2), 512, 0, stream>>>(
            x, y, imgx, imgy, bx, by, ax, ay);
    } else {
        gemm_fused<<<dim3(4, 32, 2), 512, 0, stream>>>(
            x, y, Wx, Wy, bx, by, ax, ay);
    }
    ds_combine<<<BATCH_N / 4, 256, 0, stream>>>(ax, ay, out);
}

// Round 11
// 117.144 us; speedup vs baseline: 1.1295x; 1.1295x over previous
//
#include <hip/hip_runtime.h>
#include <hip/hip_bf16.h>
#include <math.h>

#define BATCH_N 8192
#define K_DIM   2048
#define CLS     1000

typedef __attribute__((ext_vector_type(8))) short short8;
typedef __attribute__((ext_vector_type(8))) unsigned short ushort8;
typedef __attribute__((ext_vector_type(4))) float floatx4;

static __device__ __forceinline__ float softplus_fast(float z) {
    return fmaxf(z, 0.f) + __logf(1.f + __expf(-fabsf(z)));
}

static __device__ __forceinline__ ushort f2bfr(float f) {
    return __hip_bfloat16_raw(__float2bfloat16(f)).x;
}

#define BARX  __builtin_amdgcn_s_barrier()
#define LGKM0 asm volatile("s_waitcnt lgkmcnt(0)" ::: "memory")
#define SB0   __builtin_amdgcn_sched_barrier(0)
#define PRIO1 __builtin_amdgcn_s_setprio(1)
#define PRIO0 __builtin_amdgcn_s_setprio(0)

constexpr int NT = K_DIM / 32;   // 64 BK=32 sub-tiles, 32 super-tiles

// ---- 256x256 GEMM, fused fp32->bf16 staging, 4 rotating LDS slots,
// ONE barrier per TWO sub-tiles (super-tile). Round-7 structure otherwise.
// 8 waves (2 wr x 4 wc), per-wave 128x64 out, 32 MFMA/wave/sub-tile.
// Slot layout (verified, 0 bank conflicts): 16B chunk q: p=q>>3,
// c8l=(q&7)^(p&7), row=2p+(c8l>>2), k=(c8l&3)*8. Staging = reg-load fp32 ->
// cvt -> swizzled ds_write_b128; NO vmcnt at the barrier (global loads feed
// only the loading thread's own cvt -> prefetch stays in flight across it).
// Race ledger: super-tile S computes sub-tiles {2s,2s+1} (slots 2s&3,(2s+1)&3),
// writes slots (2s+2)&3,(2s+3)&3 (= S+1's read slots). Writes drained by the
// single lgkm0 before the barrier; WAR on a slot is 2 barriers after its
// last read. One barrier per super-tile is sufficient.

__global__ __launch_bounds__(512, 2)
void gemm_fused(const float* __restrict__ Xa, const float* __restrict__ Xb,
                const float* __restrict__ Wa, const float* __restrict__ Wb,
                const float* __restrict__ biasa, const float* __restrict__ biasb,
                float* __restrict__ outa, float* __restrict__ outb)
{
    // bijective XCD swizzle over the 256-block grid (256 % 8 == 0)
    int flat = blockIdx.x + 4 * (blockIdx.y + 32 * blockIdx.z);
    int sw   = (flat & 7) * 32 + (flat >> 3);
    const int bx = sw & 3, by = (sw >> 2) & 31, bz = sw >> 7;

    const float* A    = bz ? Xb : Xa;       // [8192][2048] fp32
    const float* B    = bz ? Wb : Wa;       // [1000][2048] fp32
    const float* bias = bz ? biasb : biasa;
    float* out        = bz ? outb : outa;

    __shared__ ushort As[4][256 * 32];      // 4 x 16 KiB
    __shared__ ushort Bs[4][256 * 32];      // total 128 KiB

    const int tid  = threadIdx.x;
    const int lane = tid & 63;
    const int wid  = tid >> 6;              // 8 waves: wr in {0,1}, wc in {0..3}
    const int wr = wid >> 2, wc = wid & 3;
    const int fr = lane & 15, fg = lane >> 4;
    const int brow = by * 256;
    const int bcol = bx * 256;

    // staging map: 1024 chunks per operand, 2 per thread
    size_t a_g[2], b_g[2];
    int    l_of[2];
#pragma unroll
    for (int i = 0; i < 2; ++i) {
        int q = tid + i * 512;
        int p = q >> 3, c8 = q & 7, c8l = c8 ^ (p & 7);
        int r = 2 * p + (c8l >> 2);
        int k = (c8l & 3) * 8;
        a_g[i] = (size_t)(brow + r) * K_DIM + k;
        int wrow = bcol + r; if (wrow >= CLS) wrow = CLS - 1;   // clamp pad
        b_g[i] = (size_t)wrow * K_DIM + k;
        l_of[i] = q * 8;                    // ushorts
    }

    // fragment-read offsets (verified layout)
    int afoff[8], bfoff[4];
#pragma unroll
    for (int m = 0; m < 8; ++m) {
        int row = wr * 128 + m * 16 + fr;
        int p = row >> 1;
        int c = (((row & 1) << 2) | fg) ^ (p & 7);
        afoff[m] = (p * 8 + c) * 8;
    }
#pragma unroll
    for (int n = 0; n < 4; ++n) {
        int row = wc * 64 + n * 16 + fr;
        int p = row >> 1;
        int c = (((row & 1) << 2) | fg) ^ (p & 7);
        bfoff[n] = (p * 8 + c) * 8;
    }

    floatx4 acc[8][4];
#pragma unroll
    for (int m = 0; m < 8; ++m)
#pragma unroll
        for (int n = 0; n < 4; ++n)
            acc[m][n] = (floatx4){0.f, 0.f, 0.f, 0.f};

    float4 ga[2][2], gb[2][2];              // staged fp32 (one sub-tile in flight)

#define LOADT(t_) {                                                           \
    const size_t kb_ = (size_t)(t_) * 32;                                     \
    ga[0][0] = *(const float4*)(A + a_g[0] + kb_);                            \
    ga[0][1] = *(const float4*)(A + a_g[0] + kb_ + 4);                        \
    ga[1][0] = *(const float4*)(A + a_g[1] + kb_);                            \
    ga[1][1] = *(const float4*)(A + a_g[1] + kb_ + 4);                        \
    gb[0][0] = *(const float4*)(B + b_g[0] + kb_);                            \
    gb[0][1] = *(const float4*)(B + b_g[0] + kb_ + 4);                        \
    gb[1][0] = *(const float4*)(B + b_g[1] + kb_);                            \
    gb[1][1] = *(const float4*)(B + b_g[1] + kb_ + 4);                        \
}

#define CVTW(sl_) {                                                           \
    _Pragma("unroll")                                                         \
    for (int i = 0; i < 2; ++i) {                                             \
        ushort8 ta, tb;                                                       \
        _Pragma("unroll")                                                     \
        for (int j = 0; j < 4; ++j) {                                         \
            ta[j]     = f2bfr(((const float*)&ga[i][0])[j]);                  \
            ta[j + 4] = f2bfr(((const float*)&ga[i][1])[j]);                  \
            tb[j]     = f2bfr(((const float*)&gb[i][0])[j]);                  \
            tb[j + 4] = f2bfr(((const float*)&gb[i][1])[j]);                  \
        }                                                                     \
        *(ushort8*)&As[sl_][l_of[i]] = ta;                                    \
        *(ushort8*)&Bs[sl_][l_of[i]] = tb;                                    \
    }                                                                         \
}

#define COMPUTE(t_) {                                                         \
    const ushort* asl = &As[(t_) & 3][0];                                     \
    const ushort* bsl = &Bs[(t_) & 3][0];                                     \
    short8 af[8], bf[4];                                                      \
    _Pragma("unroll")                                                         \
    for (int m = 0; m < 8; ++m) af[m] = *(const short8*)(asl + afoff[m]);     \
    _Pragma("unroll")                                                         \
    for (int n = 0; n < 4; ++n) bf[n] = *(const short8*)(bsl + bfoff[n]);     \
    PRIO1;                                                                    \
    _Pragma("unroll")                                                         \
    for (int m = 0; m < 8; ++m)                                               \
        _Pragma("unroll")                                                     \
        for (int n = 0; n < 4; ++n)                                           \
            acc[m][n] = __builtin_amdgcn_mfma_f32_16x16x32_bf16(              \
                af[m], bf[n], acc[m][n], 0, 0, 0);                            \
    PRIO0;                                                                    \
}

    // prologue: sub-tiles 0,1 staged to slots 0,1; loads of 2 in flight
    LOADT(0)
    CVTW(0)
    LOADT(1)
    CVTW(1)
    LOADT(2)
    SB0; LGKM0; BARX; SB0;

#pragma unroll 1
    for (int s = 0; s < NT / 2; ++s) {
        const int t0 = 2 * s, t1 = 2 * s + 1;
        COMPUTE(t0)
        if (t0 + 2 < NT) CVTW((t0 + 2) & 3)     // consumes loads of t0+2
        if (t0 + 3 < NT) LOADT(t0 + 3)
        COMPUTE(t1)
        if (t1 + 2 < NT) CVTW((t1 + 2) & 3)     // consumes loads of t1+2
        if (t1 + 3 < NT) LOADT(t1 + 3)
        SB0; LGKM0; BARX; SB0;                  // one barrier per super-tile
    }

    // epilogue: alpha = softplus(z + bias) + 1, predicated on col < 1000
#pragma unroll
    for (int n = 0; n < 4; ++n) {
        int col = bcol + wc * 64 + n * 16 + fr;
        if (col >= CLS) continue;
        float bv = bias[col];
#pragma unroll
        for (int m = 0; m < 8; ++m) {
#pragma unroll
            for (int j = 0; j < 4; ++j) {
                int row = brow + wr * 128 + m * 16 + fg * 4 + j;
                float z = acc[m][n][j] + bv;
                out[(size_t)row * CLS + col] = softplus_fast(z) + 1.f;
            }
        }
    }
}

// ---------------- DS combine: one wave per row, shuffle-xor reduce ----------

__global__ __launch_bounds__(256)
void ds_combine(const float* __restrict__ AX, const float* __restrict__ AY,
                float* __restrict__ out)
{
    const int row = blockIdx.x * 4 + (threadIdx.x >> 6);
    const int l = threadIdx.x & 63;
    const float* ax = AX + (size_t)row * CLS;
    const float* ay = AY + (size_t)row * CLS;

    float4 vx[4], vy[4];
    float sx = 0.f, sy = 0.f, sp = 0.f;
#pragma unroll
    for (int c = 0; c < 4; ++c) {
        int idx = l + c * 64;
        if (idx < CLS / 4) {
            vx[c] = *(const float4*)(ax + idx * 4);
            vy[c] = *(const float4*)(ay + idx * 4);
            const float* px = (const float*)&vx[c];
            const float* py = (const float*)&vy[c];
#pragma unroll
            for (int j = 0; j < 4; ++j) {
                sx += px[j]; sy += py[j];
                sp += (px[j] - 1.f) * (py[j] - 1.f);
            }
        }
    }
#pragma unroll
    for (int off = 1; off < 64; off <<= 1) {
        sx += __shfl_xor(sx, off);
        sy += __shfl_xor(sy, off);
        sp += __shfl_xor(sp, off);
    }
    const float S1 = sx, S2 = sy, P = sp;
    const float i1 = 1.f / S1, i2 = 1.f / S2;
    const float u1 = (float)CLS * i1, u2 = (float)CLS * i2;
    const float sb1 = (S1 - (float)CLS) * i1;
    const float sb2 = (S2 - (float)CLS) * i2;
    const float conf = sb1 * sb2 - P * i1 * i2;
    const float denom = 1.f - conf;
    const float idenom = 1.f / denom;
    const float Sa = (float)CLS * denom / (u1 * u2);

#pragma unroll
    for (int c = 0; c < 4; ++c) {
        int idx = l + c * 64;
        if (idx < CLS / 4) {
            float4 vo;
            const float* px = (const float*)&vx[c];
            const float* py = (const float*)&vy[c];
            float* po = (float*)&vo;
#pragma unroll
            for (int j = 0; j < 4; ++j) {
                float b1 = (px[j] - 1.f) * i1;
                float b2 = (py[j] - 1.f) * i2;
                float ba = (b1 * b2 + b1 * u2 + b2 * u1) * idenom;
                po[j] = ba * Sa + 1.f;
            }
            *(float4*)(out + (size_t)row * CLS + idx * 4) = vo;
        }
    }
}

extern "C" void kernel_launch(void* const* d_in, const int* in_sizes, int n_in,
                              void* d_out, int out_size, void* d_ws, size_t ws_size,
                              hipStream_t stream) {
    const float* x  = (const float*)d_in[0];
    const float* y  = (const float*)d_in[1];
    const float* Wx = (const float*)d_in[2];
    const float* bx = (const float*)d_in[3];
    const float* Wy = (const float*)d_in[4];
    const float* by = (const float*)d_in[5];
    float* out = (float*)d_out;
    float* ax = out + (size_t)BATCH_N * CLS;
    float* ay = ax  + (size_t)BATCH_N * CLS;

    gemm_fused<<<dim3(4, 32, 2), 512, 0, stream>>>(
        x, y, Wx, Wy, bx, by, ax, ay);
    ds_combine<<<BATCH_N / 4, 256, 0, stream>>>(ax, ay, out);
}

// Round 12
// 100.657 us; speedup vs baseline: 1.3145x; 1.1638x over previous
//
#include <hip/hip_runtime.h>
#include <hip/hip_bf16.h>
#include <math.h>

#define BATCH_N 8192
#define K_DIM   2048
#define CLS     1000

typedef __attribute__((ext_vector_type(8))) short short8;
typedef __attribute__((ext_vector_type(8))) unsigned short ushort8;
typedef __attribute__((ext_vector_type(4))) float floatx4;

static __device__ __forceinline__ float softplus_fast(float z) {
    return fmaxf(z, 0.f) + __logf(1.f + __expf(-fabsf(z)));
}

static __device__ __forceinline__ ushort f2bfr(float f) {
    return __hip_bfloat16_raw(__float2bfloat16(f)).x;
}

#define BARX  __builtin_amdgcn_s_barrier()
#define LGKM0 asm volatile("s_waitcnt lgkmcnt(0)" ::: "memory")
#define SB0   __builtin_amdgcn_sched_barrier(0)
#define PRIO1 __builtin_amdgcn_s_setprio(1)
#define PRIO0 __builtin_amdgcn_s_setprio(0)

constexpr int NT = K_DIM / 32;   // 64 K-tiles

// ---- 256x256 GEMM, fused fp32->bf16 staging, BK=32, 2-slot dbuf, 1 bar/tile
// Round-7 kernel with 16 WAVES (1024 thr, 4x4 wave grid, per-wave 64x64 out):
// acc drops 128->64 AGPR => ~140 unified regs/wave => 3 waves/SIMD resident
// (12 waves/CU, +50% latency hiding vs r7's 2/SIMD). Per-thread staging work
// halves (1 chunk per operand). NO forced reg cap (r8 lesson).
// Slot layout (verified, 0 bank conflicts): 16B chunk q: p=q>>3,
// c8l=(q&7)^(p&7), row=2p+(c8l>>2), k=(c8l&3)*8. Staging = reg-load fp32 ->
// cvt -> swizzled ds_write_b128; NO vmcnt at the barrier (global loads feed
// only the loading thread's own cvt -> prefetch stays in flight across it).

__global__ __launch_bounds__(1024, 2)
void gemm_fused(const float* __restrict__ Xa, const float* __restrict__ Xb,
                const float* __restrict__ Wa, const float* __restrict__ Wb,
                const float* __restrict__ biasa, const float* __restrict__ biasb,
                float* __restrict__ outa, float* __restrict__ outb)
{
    // bijective XCD swizzle over the 256-block grid (256 % 8 == 0)
    int flat = blockIdx.x + 4 * (blockIdx.y + 32 * blockIdx.z);
    int sw   = (flat & 7) * 32 + (flat >> 3);
    const int bx = sw & 3, by = (sw >> 2) & 31, bz = sw >> 7;

    const float* A    = bz ? Xb : Xa;       // [8192][2048] fp32
    const float* B    = bz ? Wb : Wa;       // [1000][2048] fp32
    const float* bias = bz ? biasb : biasa;
    float* out        = bz ? outb : outa;

    __shared__ ushort As[2][256 * 32];      // 16 KiB per slot
    __shared__ ushort Bs[2][256 * 32];      // total 64 KiB

    const int tid  = threadIdx.x;
    const int lane = tid & 63;
    const int wid  = tid >> 6;              // 16 waves: wr, wc in {0..3}
    const int wr = wid >> 2, wc = wid & 3;
    const int fr = lane & 15, fg = lane >> 4;
    const int brow = by * 256;
    const int bcol = bx * 256;

    // staging map: 1024 chunks per operand, ONE per thread
    size_t a_g, b_g;
    int    l_of;
    {
        int q = tid;
        int p = q >> 3, c8 = q & 7, c8l = c8 ^ (p & 7);
        int r = 2 * p + (c8l >> 2);
        int k = (c8l & 3) * 8;
        a_g = (size_t)(brow + r) * K_DIM + k;
        int wrow = bcol + r; if (wrow >= CLS) wrow = CLS - 1;   // clamp pad
        b_g = (size_t)wrow * K_DIM + k;
        l_of = q * 8;                       // ushorts
    }

    // fragment-read offsets (verified layout); per-wave 64x64 output
    int afoff[4], bfoff[4];
#pragma unroll
    for (int m = 0; m < 4; ++m) {
        int row = wr * 64 + m * 16 + fr;
        int p = row >> 1;
        int c = (((row & 1) << 2) | fg) ^ (p & 7);
        afoff[m] = (p * 8 + c) * 8;
    }
#pragma unroll
    for (int n = 0; n < 4; ++n) {
        int row = wc * 64 + n * 16 + fr;
        int p = row >> 1;
        int c = (((row & 1) << 2) | fg) ^ (p & 7);
        bfoff[n] = (p * 8 + c) * 8;
    }

    floatx4 acc[4][4];
#pragma unroll
    for (int m = 0; m < 4; ++m)
#pragma unroll
        for (int n = 0; n < 4; ++n)
            acc[m][n] = (floatx4){0.f, 0.f, 0.f, 0.f};

    float4 ga[2], gb[2];                    // staged fp32 (one chunk each)

#define LOADT(t_) {                                                           \
    const size_t kb_ = (size_t)(t_) * 32;                                     \
    ga[0] = *(const float4*)(A + a_g + kb_);                                  \
    ga[1] = *(const float4*)(A + a_g + kb_ + 4);                              \
    gb[0] = *(const float4*)(B + b_g + kb_);                                  \
    gb[1] = *(const float4*)(B + b_g + kb_ + 4);                              \
}

#define CVTW(sl_) {                                                           \
    ushort8 ta, tb;                                                           \
    _Pragma("unroll")                                                         \
    for (int j = 0; j < 4; ++j) {                                             \
        ta[j]     = f2bfr(((const float*)&ga[0])[j]);                         \
        ta[j + 4] = f2bfr(((const float*)&ga[1])[j]);                         \
        tb[j]     = f2bfr(((const float*)&gb[0])[j]);                         \
        tb[j + 4] = f2bfr(((const float*)&gb[1])[j]);                         \
    }                                                                         \
    *(ushort8*)&As[sl_][l_of] = ta;                                           \
    *(ushort8*)&Bs[sl_][l_of] = tb;                                           \
}

    // prologue: tile 0 staged to slot 0; tile 1 loads in flight
    LOADT(0)
    CVTW(0)
    LOADT(1)
    SB0; LGKM0; BARX; SB0;

#pragma unroll 1
    for (int t = 0; t < NT; ++t) {
        const ushort* asl = &As[t & 1][0];
        const ushort* bsl = &Bs[t & 1][0];
        short8 af[4], bf[4];
#pragma unroll
        for (int m = 0; m < 4; ++m) af[m] = *(const short8*)(asl + afoff[m]);
#pragma unroll
        for (int n = 0; n < 4; ++n) bf[n] = *(const short8*)(bsl + bfoff[n]);

        PRIO1;
#pragma unroll
        for (int m = 0; m < 4; ++m)
#pragma unroll
            for (int n = 0; n < 4; ++n)
                acc[m][n] = __builtin_amdgcn_mfma_f32_16x16x32_bf16(
                    af[m], bf[n], acc[m][n], 0, 0, 0);
        PRIO0;

        if (t + 1 < NT) CVTW((t + 1) & 1)       // consumes loads of tile t+1
        if (t + 2 < NT) LOADT(t + 2)            // issue early; used next iter
        SB0; LGKM0; BARX; SB0;                  // NO vmcnt drain
    }

    // epilogue: alpha = softplus(z + bias) + 1, predicated on col < 1000
#pragma unroll
    for (int n = 0; n < 4; ++n) {
        int col = bcol + wc * 64 + n * 16 + fr;
        if (col >= CLS) continue;
        float bv = bias[col];
#pragma unroll
        for (int m = 0; m < 4; ++m) {
#pragma unroll
            for (int j = 0; j < 4; ++j) {
                int row = brow + wr * 64 + m * 16 + fg * 4 + j;
                float z = acc[m][n][j] + bv;
                out[(size_t)row * CLS + col] = softplus_fast(z) + 1.f;
            }
        }
    }
}

// ---------------- DS combine: one wave per row, shuffle-xor reduce ----------

__global__ __launch_bounds__(256)
void ds_combine(const float* __restrict__ AX, const float* __restrict__ AY,
                float* __restrict__ out)
{
    const int row = blockIdx.x * 4 + (threadIdx.x >> 6);
    const int l = threadIdx.x & 63;
    const float* ax = AX + (size_t)row * CLS;
    const float* ay = AY + (size_t)row * CLS;

    float4 vx[4], vy[4];
    float sx = 0.f, sy = 0.f, sp = 0.f;
#pragma unroll
    for (int c = 0; c < 4; ++c) {
        int idx = l + c * 64;
        if (idx < CLS / 4) {
            vx[c] = *(const float4*)(ax + idx * 4);
            vy[c] = *(const float4*)(ay + idx * 4);
            const float* px = (const float*)&vx[c];
            const float* py = (const float*)&vy[c];
#pragma unroll
            for (int j = 0; j < 4; ++j) {
                sx += px[j]; sy += py[j];
                sp += (px[j] - 1.f) * (py[j] - 1.f);
            }
        }
    }
#pragma unroll
    for (int off = 1; off < 64; off <<= 1) {
        sx += __shfl_xor(sx, off);
        sy += __shfl_xor(sy, off);
        sp += __shfl_xor(sp, off);
    }
    const float S1 = sx, S2 = sy, P = sp;
    const float i1 = 1.f / S1, i2 = 1.f / S2;
    const float u1 = (float)CLS * i1, u2 = (float)CLS * i2;
    const float sb1 = (S1 - (float)CLS) * i1;
    const float sb2 = (S2 - (float)CLS) * i2;
    const float conf = sb1 * sb2 - P * i1 * i2;
    const float denom = 1.f - conf;
    const float idenom = 1.f / denom;
    const float Sa = (float)CLS * denom / (u1 * u2);

#pragma unroll
    for (int c = 0; c < 4; ++c) {
        int idx = l + c * 64;
        if (idx < CLS / 4) {
            float4 vo;
            const float* px = (const float*)&vx[c];
            const float* py = (const float*)&vy[c];
            float* po = (float*)&vo;
#pragma unroll
            for (int j = 0; j < 4; ++j) {
                float b1 = (px[j] - 1.f) * i1;
                float b2 = (py[j] - 1.f) * i2;
                float ba = (b1 * b2 + b1 * u2 + b2 * u1) * idenom;
                po[j] = ba * Sa + 1.f;
            }
            *(float4*)(out + (size_t)row * CLS + idx * 4) = vo;
        }
    }
}

extern "C" void kernel_launch(void* const* d_in, const int* in_sizes, int n_in,
                              void* d_out, int out_size, void* d_ws, size_t ws_size,
                              hipStream_t stream) {
    const float* x  = (const float*)d_in[0];
    const float* y  = (const float*)d_in[1];
    const float* Wx = (const float*)d_in[2];
    const float* bx = (const float*)d_in[3];
    const float* Wy = (const float*)d_in[4];
    const float* by = (const float*)d_in[5];
    float* out = (float*)d_out;
    float* ax = out + (size_t)BATCH_N * CLS;
    float* ay = ax  + (size_t)BATCH_N * CLS;

    gemm_fused<<<dim3(4, 32, 2), 1024, 0, stream>>>(
        x, y, Wx, Wy, bx, by, ax, ay);
    ds_combine<<<BATCH_N / 4, 256, 0, stream>>>(ax, ay, out);
}